// Round 16
// baseline (543.783 us; speedup 1.0000x reference)
//
#include <hip/hip_runtime.h>
#include <hip/hip_bf16.h>
#include <cstdint>

typedef unsigned short u16;
typedef unsigned int u32;
typedef __bf16 bf16x8 __attribute__((ext_vector_type(8)));
typedef float f32x4 __attribute__((ext_vector_type(4)));

constexpr int Bb = 16, Tt = 1024, Ss = 2048, Hh = 1024;
constexpr long BT = (long)Bb * Tt;

__device__ __forceinline__ u16 f2bf(float x) {
  u32 u = __builtin_bit_cast(u32, x);
  u32 r = (u + 0x7fffu + ((u >> 16) & 1u)) >> 16;
  return (u16)r;
}
__device__ __forceinline__ float bf2f(u16 h) {
  u32 u = ((u32)h) << 16;
  return __builtin_bit_cast(float, u);
}

__device__ __forceinline__ void gload16(const u16* g, u16* lds) {
  __builtin_amdgcn_global_load_lds(
      (const __attribute__((address_space(1))) u32*)g,
      (__attribute__((address_space(3))) u32*)lds, 16, 0, 0);
}

#define MFMA16(a, b, c) __builtin_amdgcn_mfma_f32_16x16x32_bf16(a, b, c, 0, 0, 0)

// r16 = r15 + hoisted LDS fragment addresses. VALUBusy 21% was per-iteration
// recomputation of 24 ds_read addresses whose only runtime part is a lane
// swizzle fixed per (parity,kk). Precompute 8 lane pointers (aptr/bptr
// [parity][kk], +8 VGPR) so every fragment read is ptr + compile-time
// m*2048 / n*2048 — folds into the ds_read_b128 offset: immediate; zero
// per-iteration address VALU. Same bytes read -> bit-identical (canary
// 0.01367188). Everything else identical to r15 (tight/deep vmcnt, r14
// merged phB sync, r13 bh-dangle, 2-phase, chunk^=(row&7) swizzle, XCD
// bijective remap).
// Virtual-K split GEMM: K' = NPASS*K, plane pair selected per K-tile.
//   NPASS==3: Ahi*Bhi + Alo*Bhi + Ahi*Blo ; NPASS==2: Ahi*Bhi + Ahi*Blo ; NPASS==1: Ahi*Bhi
// EPI: 0 fp32 store; 1 (+bias) split hi/lo bf16; 2 tanh(+bias) fp32; 3 hi-only bf16.
template <int NPASS, int K, int EPI>
__global__ __launch_bounds__(512, 2) void gemm8(
    const u16* __restrict__ Ahi, const u16* __restrict__ Alo,
    const u16* __restrict__ Bhi, const u16* __restrict__ Blo,
    int lda0, int lda1, int ldb,
    long sA, long sB, long sC,
    const float* __restrict__ bias,
    float* __restrict__ Cf, u16* __restrict__ Chi, u16* __restrict__ Clo,
    int ldc) {
  constexpr int K64 = K / 64;
  constexpr int NT = NPASS * K64;
  __shared__ __attribute__((aligned(16))) u16 smem[2][2][2][128][64];  // [buf][A/B][half][row][col]
  const int tid = threadIdx.x;
  const int lane = tid & 63;
  const int wave = tid >> 6;
  const int wr = wave >> 2;  // 0..1 (M half)
  const int wc = wave & 3;   // 0..3 (N quarter)
  const int l15 = lane & 15, l7 = lane & 7, kl = lane >> 4;

  // T1: bijective XCD remap + bn-fastest tile decomposition
  const u32 gx = gridDim.x, gy = gridDim.y;
  const u32 flat = blockIdx.x + gx * (blockIdx.y + gy * blockIdx.z);
  const u32 nwg = gx * gy * gridDim.z;
  const u32 chunk = nwg >> 3;
  const u32 l = (flat & 7) * chunk + (flat >> 3);
  const u32 tpb = gx * gy;
  const u32 bzi = l / tpb;
  const u32 rr2 = l - bzi * tpb;
  const long bm = (long)(rr2 / gy) * 256;
  const long bn = (long)(rr2 % gy) * 256;
  const long bz = bzi;

  auto stage = [&](int tt, int op, int half, int buf) {
    if (tt >= NT) return;
    const int pass = tt / K64;
    const int kk0 = (tt % K64) * 64;
    const u16* src;
    long ld;
    if (op == 0) {
      if constexpr (NPASS == 3) {
        src = (pass == 1) ? Alo : Ahi;
        ld = (pass == 1) ? lda1 : lda0;
      } else {
        src = Ahi;
        ld = lda0;
      }
    } else {
      if constexpr (NPASS >= 2) {
        src = (pass == ((NPASS == 3) ? 2 : 1)) ? Blo : Bhi;
      } else {
        src = Bhi;
      }
      ld = ldb;
    }
    const long bstr = op ? sB : sA;
    const long rb = (op ? bn : bm) + (long)half * 128;
    const int r0 = tid >> 3;                 // 0..63 (row within 64-row slab)
    const int c0 = (tid & 7) ^ (r0 & 7);     // pre-swizzled source chunk
    const u16* g = src + bz * bstr + (rb + r0) * ld + kk0 + c0 * 8;
    u16* lp = &smem[buf][op][half][0][0] + (tid >> 6) * 512;  // wave-uniform dest
    gload16(g, lp);
    gload16(g + 64 * ld, lp + 4096);         // rows +64: (r0+64)&7 == r0&7
  };

  // hoisted lane pointers: [parity][kk]; fragment read = ptr + m*2048 (imm)
  const char* aptr[2][2];
  const char* bptr[2][2];
#pragma unroll
  for (int p = 0; p < 2; ++p)
#pragma unroll
    for (int kk = 0; kk < 2; ++kk) {
      const int swz = ((((kk << 2) + kl) ^ l7) << 4);
      aptr[p][kk] = (const char*)&smem[p][0][wr][0][0] + l15 * 128 + swz;
      bptr[p][kk] = (const char*)&smem[p][1][wc >> 1][0][0] + (wc & 1) * 8192 +
                    l15 * 128 + swz;
    }

  f32x4 acc[8][4] = {};

  // prologue: stage tile0 fully, CONFIRM it, then put tile1 in flight.
  stage(0, 1, 0, 0); stage(0, 1, 1, 0); stage(0, 0, 0, 0); stage(0, 0, 1, 0);
  asm volatile("s_waitcnt vmcnt(0)" ::: "memory");
  __builtin_amdgcn_s_barrier();
  stage(1, 0, 0, 1); stage(1, 0, 1, 1);   // A(1) first (drained first)
  stage(1, 1, 0, 1); stage(1, 1, 1, 1);   // then B(1)

  bf16x8 af[8][2], bl[2][2], bh[2][2];

#pragma unroll 1
  for (int t2 = 0; t2 < NT; t2 += 2) {
#pragma unroll
    for (int u = 0; u < 2; ++u) {
      const int t = t2 + u;
      const int P = u;  // buffer parity (t2 even) — compile-time in unrolled body
      // ---- Phase A (stage-free): read af[8]+bl; MFMA n0-1; issue bh at the
      //      end (dangles across the barrier)
#pragma unroll
      for (int m = 0; m < 8; ++m) {
        af[m][0] = *(const bf16x8*)(aptr[P][0] + m * 2048);
        af[m][1] = *(const bf16x8*)(aptr[P][1] + m * 2048);
      }
#pragma unroll
      for (int n = 0; n < 2; ++n) {
        bl[n][0] = *(const bf16x8*)(bptr[P][0] + n * 2048);
        bl[n][1] = *(const bf16x8*)(bptr[P][1] + n * 2048);
      }
      __builtin_amdgcn_s_setprio(1);
#pragma unroll
      for (int m = 0; m < 4; ++m)
#pragma unroll
        for (int n = 0; n < 2; ++n) {
          acc[m][n] = MFMA16(af[m][0], bl[n][0], acc[m][n]);
          acc[m][n] = MFMA16(af[m][1], bl[n][1], acc[m][n]);
        }
#pragma unroll
      for (int m = 0; m < 4; ++m)
#pragma unroll
        for (int n = 0; n < 2; ++n) {
          acc[4 + m][n] = MFMA16(af[4 + m][0], bl[n][0], acc[4 + m][n]);
          acc[4 + m][n] = MFMA16(af[4 + m][1], bl[n][1], acc[4 + m][n]);
        }
      __builtin_amdgcn_s_setprio(0);
      __builtin_amdgcn_sched_barrier(0);   // pin: all af/bl reads issued first
#pragma unroll
      for (int n = 0; n < 2; ++n) {
        bh[n][0] = *(const bf16x8*)(bptr[P][0] + (2 + n) * 2048);
        bh[n][1] = *(const bf16x8*)(bptr[P][1] + (2 + n) * 2048);
      }
      __builtin_amdgcn_sched_barrier(0);   // pin: bh last in DS issue order
      asm volatile("s_waitcnt lgkmcnt(4)" ::: "memory");  // af+bl done; bh dangles
      __builtin_amdgcn_s_barrier();
      // ---- Phase B: stage A(t+2); MFMA n2-3; lgkm(0) [bh drained]; stage
      //      B(t+2) [bh-region now dead]; tight counted vmcnt; one barrier.
      stage(t + 2, 0, 0, P);
      stage(t + 2, 0, 1, P);
      __builtin_amdgcn_s_setprio(1);
#pragma unroll
      for (int m = 0; m < 4; ++m)
#pragma unroll
        for (int n = 0; n < 2; ++n) {
          acc[4 + m][2 + n] = MFMA16(af[4 + m][0], bh[n][0], acc[4 + m][2 + n]);
          acc[4 + m][2 + n] = MFMA16(af[4 + m][1], bh[n][1], acc[4 + m][2 + n]);
        }
#pragma unroll
      for (int m = 0; m < 4; ++m)
#pragma unroll
        for (int n = 0; n < 2; ++n) {
          acc[m][2 + n] = MFMA16(af[m][0], bh[n][0], acc[m][2 + n]);
          acc[m][2 + n] = MFMA16(af[m][1], bh[n][1], acc[m][2 + n]);
        }
      __builtin_amdgcn_s_setprio(0);
      asm volatile("s_waitcnt lgkmcnt(0)" ::: "memory");  // bh fully drained
      stage(t + 2, 1, 0, P);
      stage(t + 2, 1, 1, P);
      // outstanding: A(t+1),B(t+1),A(t+2),B(t+2) = 8 (steady state).
      if (t < NT - 2)
        asm volatile("s_waitcnt vmcnt(4)" ::: "memory");
      else
        asm volatile("s_waitcnt vmcnt(0)" ::: "memory");
      __builtin_amdgcn_s_barrier();
    }
  }

  // epilogue
  const int fr = l15;
  const int rg = (lane >> 4) * 4;
#pragma unroll
  for (int m = 0; m < 8; ++m) {
#pragma unroll
    for (int n = 0; n < 4; ++n) {
      long col = bn + wc * 64 + n * 16 + fr;
      float bv = 0.f;
      if constexpr (EPI == 1 || EPI == 2) {
        if (bias) bv = bias[col];
      }
#pragma unroll
      for (int j = 0; j < 4; ++j) {
        long row = bm + wr * 128 + m * 16 + rg + j;
        long idx = bz * sC + row * (long)ldc + col;
        float v = acc[m][n][j];
        if constexpr (EPI == 0) {
          Cf[idx] = v;
        } else if constexpr (EPI == 1) {
          v += bv;
          u16 h = f2bf(v);
          u16 l2 = f2bf(v - bf2f(h));
          Chi[idx] = h;
          Clo[idx] = l2;
        } else if constexpr (EPI == 2) {
          Cf[idx] = tanhf(v + bv);
        } else {
          Chi[idx] = f2bf(v);
        }
      }
    }
  }
}

// input [BT,1024] fp32 -> cat hi cols [1024..2048) (row stride 2048) + inLo [BT,1024]
__global__ void split_input_k(const float* __restrict__ in, u16* __restrict__ catHi,
                              u16* __restrict__ inLo) {
  long i = (long)blockIdx.x * 256 + threadIdx.x;
  const float4 v = ((const float4*)in)[i];
  long r = i >> 8;
  int c = (int)(i & 255);
  ushort4 hs, ls;
  hs.x = f2bf(v.x); ls.x = f2bf(v.x - bf2f(hs.x));
  hs.y = f2bf(v.y); ls.y = f2bf(v.y - bf2f(hs.y));
  hs.z = f2bf(v.z); ls.z = f2bf(v.z - bf2f(hs.z));
  hs.w = f2bf(v.w); ls.w = f2bf(v.w - bf2f(hs.w));
  *(ushort4*)&catHi[r * 2048 + 1024 + c * 4] = hs;
  *(ushort4*)&inLo[r * 1024 + c * 4] = ls;
}

__global__ void split_plain_k(const float* __restrict__ src, u16* __restrict__ hi,
                              u16* __restrict__ lo) {
  long i = (long)blockIdx.x * 256 + threadIdx.x;
  const float4 v = ((const float4*)src)[i];
  long base = i * 4;
  ushort4 hs, ls;
  hs.x = f2bf(v.x); ls.x = f2bf(v.x - bf2f(hs.x));
  hs.y = f2bf(v.y); ls.y = f2bf(v.y - bf2f(hs.y));
  hs.z = f2bf(v.z); ls.z = f2bf(v.z - bf2f(hs.z));
  hs.w = f2bf(v.w); ls.w = f2bf(v.w - bf2f(hs.w));
  *(ushort4*)&hi[base] = hs;
  *(ushort4*)&lo[base] = ls;
}

// vectorized ctx split+transpose (r12): float4 loads, ushort4 stores,
// LDS [64][68] transpose for coalesced ctxT writes.
__global__ __launch_bounds__(256) void ctx_split_trans_k(
    const float* __restrict__ ctx, u16* __restrict__ ctxHi,
    u16* __restrict__ ctxLo, u16* __restrict__ ctxTHi) {
  __shared__ u16 th[64][68];
  const int s0 = blockIdx.x * 64, h0 = blockIdx.y * 64, b = blockIdx.z;
  const int tid = threadIdx.x;
#pragma unroll
  for (int i = 0; i < 4; ++i) {
    int fl = i * 256 + tid;   // 0..1023
    int s = fl >> 4;          // 0..63
    int hq = fl & 15;         // float4 index within 64-col row
    long gi = ((long)b * Ss + s0 + s) * Hh + h0 + hq * 4;
    float4 v = *(const float4*)&ctx[gi];
    ushort4 hs, ls;
    hs.x = f2bf(v.x); ls.x = f2bf(v.x - bf2f(hs.x));
    hs.y = f2bf(v.y); ls.y = f2bf(v.y - bf2f(hs.y));
    hs.z = f2bf(v.z); ls.z = f2bf(v.z - bf2f(hs.z));
    hs.w = f2bf(v.w); ls.w = f2bf(v.w - bf2f(hs.w));
    *(ushort4*)&ctxHi[gi] = hs;
    *(ushort4*)&ctxLo[gi] = ls;
    *(ushort4*)&th[s][hq * 4] = hs;
  }
  __syncthreads();
#pragma unroll
  for (int i = 0; i < 4; ++i) {
    int fl = i * 256 + tid;
    int h = fl >> 4;          // 0..63
    int sq = fl & 15;         // ushort4 index along s
    ushort4 t;
    t.x = th[sq * 4 + 0][h];
    t.y = th[sq * 4 + 1][h];
    t.z = th[sq * 4 + 2][h];
    t.w = th[sq * 4 + 3][h];
    long go = ((long)b * Hh + h0 + h) * Ss + s0 + sq * 4;
    *(ushort4*)&ctxTHi[go] = t;
  }
}

__global__ __launch_bounds__(256) void softmax_k(const float* __restrict__ sc,
                                                 u16* __restrict__ alignHi) {
  long row = blockIdx.x;
  const float* x = sc + row * 2048;
  int tid = threadIdx.x;
  int lane = tid & 63, wave = tid >> 6;
  float4 v0 = ((const float4*)x)[tid];
  float4 v1 = ((const float4*)x)[tid + 256];
  float m = fmaxf(fmaxf(fmaxf(v0.x, v0.y), fmaxf(v0.z, v0.w)),
                  fmaxf(fmaxf(v1.x, v1.y), fmaxf(v1.z, v1.w)));
#pragma unroll
  for (int o = 1; o < 64; o <<= 1) m = fmaxf(m, __shfl_xor(m, o));
  __shared__ float red[8];
  if (lane == 0) red[wave] = m;
  __syncthreads();
  m = fmaxf(fmaxf(red[0], red[1]), fmaxf(red[2], red[3]));
  float e0 = expf(v0.x - m), e1 = expf(v0.y - m), e2 = expf(v0.z - m), e3 = expf(v0.w - m);
  float e4 = expf(v1.x - m), e5 = expf(v1.y - m), e6 = expf(v1.z - m), e7 = expf(v1.w - m);
  float s = ((e0 + e1) + (e2 + e3)) + ((e4 + e5) + (e6 + e7));
#pragma unroll
  for (int o = 1; o < 64; o <<= 1) s += __shfl_xor(s, o);
  if (lane == 0) red[4 + wave] = s;
  __syncthreads();
  s = (red[4] + red[5]) + (red[6] + red[7]);
  float inv = 1.0f / s;
  ushort4 h0, h1;
  h0.x = f2bf(e0 * inv); h0.y = f2bf(e1 * inv); h0.z = f2bf(e2 * inv); h0.w = f2bf(e3 * inv);
  h1.x = f2bf(e4 * inv); h1.y = f2bf(e5 * inv); h1.z = f2bf(e6 * inv); h1.w = f2bf(e7 * inv);
  *(ushort4*)&alignHi[row * 2048 + tid * 4] = h0;
  *(ushort4*)&alignHi[row * 2048 + 1024 + tid * 4] = h1;
}

extern "C" void kernel_launch(void* const* d_in, const int* in_sizes, int n_in,
                              void* d_out, int out_size, void* d_ws, size_t ws_size,
                              hipStream_t stream) {
  const float* input = (const float*)d_in[0];
  const float* context = (const float*)d_in[1];
  const float* affine_w = (const float*)d_in[2];
  const float* affine_b = (const float*)d_in[3];
  const float* mlp_w = (const float*)d_in[4];
  const float* mlp_b = (const float*)d_in[5];

  size_t off = 0;
  char* ws = (char*)d_ws;
  auto take = [&](size_t bytes) -> void* {
    void* p = ws + off;
    off += (bytes + 255) & ~(size_t)255;
    return p;
  };
  const size_t NBIG = 33554432;  // BT*2048
  u16* catHi   = (u16*)take(NBIG * 2);   // 64MB  [c | input] hi, [BT,2048]
  u16* inLo    = (u16*)take(NBIG);       // 32MB  input lo [BT,1024]
  u16* ctxHi   = (u16*)take(NBIG * 2);   // 64MB  [B,S,H]
  u16* ctxLo   = (u16*)take(NBIG * 2);   // 64MB
  u16* ctxTHi  = (u16*)take(NBIG * 2);   // 64MB  [B,H,S]
  u16* alignHi = (u16*)take(NBIG * 2);   // 64MB  [BT,S]
  u16* wHi  = (u16*)take(1048576 * 2);
  u16* wLo  = (u16*)take(1048576 * 2);
  u16* mwHi = (u16*)take(2097152 * 2);
  u16* mwLo = (u16*)take(2097152 * 2);
  size_t fixed_off = off;
  // scores chunk: nbc batches at 8MB each, adaptive to ws_size
  int nbc = 16;
  while (nbc > 2 && fixed_off + (size_t)nbc * Tt * Ss * 4 + 4096 > ws_size) nbc >>= 1;
  float* scores = (float*)take((size_t)nbc * Tt * Ss * 4);
  // h_t hi/lo planes live in d_out (overwritten by the final fp32 output)
  u16* htHi = (u16*)d_out;
  u16* htLo = htHi + 16777216;

  if (ws_size < off) {  // fail soft: absmax == max|ref| signals ws starvation
    hipMemsetAsync(d_out, 0, (size_t)out_size * 4, stream);
    return;
  }

  split_plain_k<<<1024, 256, 0, stream>>>(affine_w, wHi, wLo);
  split_plain_k<<<2048, 256, 0, stream>>>(mlp_w, mwHi, mwLo);
  split_input_k<<<16384, 256, 0, stream>>>(input, catHi, inLo);
  ctx_split_trans_k<<<dim3(32, 16, 16), 256, 0, stream>>>(context, ctxHi, ctxLo,
                                                          ctxTHi);
  // GEMM1: h_t = input*Wa^T + b  (M=16384,N=1024,K=1024, 3-pass) -> ht hi/lo in d_out
  gemm8<3, 1024, 1><<<dim3(64, 4, 1), 512, 0, stream>>>(
      catHi + 1024, inLo, wHi, wLo, 2048, 1024, 1024, 0, 0, 0, affine_b,
      nullptr, htHi, htLo, 1024);
  // GEMM2 + softmax in chunks of nbc batches
  for (int ch = 0; ch < 16 / nbc; ++ch) {
    long bo = (long)ch * nbc;
    gemm8<3, 1024, 0><<<dim3(4, 8, nbc), 512, 0, stream>>>(
        htHi + bo * Tt * Hh, htLo + bo * Tt * Hh, ctxHi + bo * Ss * Hh,
        ctxLo + bo * Ss * Hh, 1024, 1024, 1024, (long)Tt * Hh, (long)Ss * Hh,
        (long)Tt * Ss, nullptr, scores, nullptr, nullptr, 2048);
    softmax_k<<<nbc * 1024, 256, 0, stream>>>(scores, alignHi + bo * Tt * Ss);
  }
  // GEMM3: c[b] = align[b]*ctxT[b]^T (M=1024,N=1024,K=2048, 1-pass) -> cat cols [0,1024)
  gemm8<1, 2048, 3><<<dim3(4, 4, 16), 512, 0, stream>>>(
      alignHi, nullptr, ctxTHi, nullptr, 2048, 0, 2048, (long)Tt * Ss, (long)Hh * Ss,
      (long)Tt * 2048, nullptr, nullptr, catHi, nullptr, 2048);
  // GEMM4: out = tanh(cat*Wmlp^T + b)  (M=16384,N=1024,K=2048, 1-pass)
  gemm8<1, 2048, 2><<<dim3(64, 4, 1), 512, 0, stream>>>(
      catHi, nullptr, mwHi, nullptr, 2048, 0, 2048, 0, 0, 0, mlp_b, (float*)d_out,
      nullptr, nullptr, 1024);
  (void)in_sizes; (void)n_in; (void)ws_size;
}

// Round 17
// 531.291 us; speedup vs baseline: 1.0235x; 1.0235x over previous
//
#include <hip/hip_runtime.h>
#include <hip/hip_bf16.h>
#include <cstdint>

typedef unsigned short u16;
typedef unsigned int u32;
typedef __bf16 bf16x8 __attribute__((ext_vector_type(8)));
typedef float f32x4 __attribute__((ext_vector_type(4)));

constexpr int Bb = 16, Tt = 1024, Ss = 2048, Hh = 1024;
constexpr long BT = (long)Bb * Tt;

__device__ __forceinline__ u16 f2bf(float x) {
  u32 u = __builtin_bit_cast(u32, x);
  u32 r = (u + 0x7fffu + ((u >> 16) & 1u)) >> 16;
  return (u16)r;
}
__device__ __forceinline__ float bf2f(u16 h) {
  u32 u = ((u32)h) << 16;
  return __builtin_bit_cast(float, u);
}

__device__ __forceinline__ void gload16(const u16* g, u16* lds) {
  __builtin_amdgcn_global_load_lds(
      (const __attribute__((address_space(1))) u32*)g,
      (__attribute__((address_space(3))) u32*)lds, 16, 0, 0);
}

#define MFMA16(a, b, c) __builtin_amdgcn_mfma_f32_16x16x32_bf16(a, b, c, 0, 0, 0)

// r17: per-shape schedule hybrid. r11 and r15 both showed the same pattern:
// schedule tweaks that help the 2-block/CU GEMM2 (512 blocks) HURT the
// 1-block/CU GEMMs (256 blocks) — with no co-resident block, tighter
// serialization has nothing to hide under. So: SCHED=1 (r15/r16 schedule,
// stage-free phA + deep tight vmcnt) for GEMM2; SCHED=0 (r14 schedule,
// B staged in phA, A staged at phB top, merged phB sync) for GEMM1/3/4.
// Both paths bit-identical to their verified rounds -> canary 0.01367188.
// Common: 256x256 tile, BK=64, 8-wave 2Mx4N, chunk^=(row&7) LDS swizzle,
// XCD bijective remap, bh-dangle (r13), hoisted LDS lane pointers (r16).
// Virtual-K split GEMM: K' = NPASS*K, plane pair selected per K-tile.
//   NPASS==3: Ahi*Bhi + Alo*Bhi + Ahi*Blo ; NPASS==2: Ahi*Bhi + Ahi*Blo ; NPASS==1: Ahi*Bhi
// EPI: 0 fp32 store; 1 (+bias) split hi/lo bf16; 2 tanh(+bias) fp32; 3 hi-only bf16.
template <int NPASS, int K, int EPI, int SCHED>
__global__ __launch_bounds__(512, 2) void gemm8(
    const u16* __restrict__ Ahi, const u16* __restrict__ Alo,
    const u16* __restrict__ Bhi, const u16* __restrict__ Blo,
    int lda0, int lda1, int ldb,
    long sA, long sB, long sC,
    const float* __restrict__ bias,
    float* __restrict__ Cf, u16* __restrict__ Chi, u16* __restrict__ Clo,
    int ldc) {
  constexpr int K64 = K / 64;
  constexpr int NT = NPASS * K64;
  __shared__ __attribute__((aligned(16))) u16 smem[2][2][2][128][64];  // [buf][A/B][half][row][col]
  const int tid = threadIdx.x;
  const int lane = tid & 63;
  const int wave = tid >> 6;
  const int wr = wave >> 2;  // 0..1 (M half)
  const int wc = wave & 3;   // 0..3 (N quarter)
  const int l15 = lane & 15, l7 = lane & 7, kl = lane >> 4;

  // T1: bijective XCD remap + bn-fastest tile decomposition
  const u32 gx = gridDim.x, gy = gridDim.y;
  const u32 flat = blockIdx.x + gx * (blockIdx.y + gy * blockIdx.z);
  const u32 nwg = gx * gy * gridDim.z;
  const u32 chunk = nwg >> 3;
  const u32 l = (flat & 7) * chunk + (flat >> 3);
  const u32 tpb = gx * gy;
  const u32 bzi = l / tpb;
  const u32 rr2 = l - bzi * tpb;
  const long bm = (long)(rr2 / gy) * 256;
  const long bn = (long)(rr2 % gy) * 256;
  const long bz = bzi;

  auto stage = [&](int tt, int op, int half, int buf) {
    if (tt >= NT) return;
    const int pass = tt / K64;
    const int kk0 = (tt % K64) * 64;
    const u16* src;
    long ld;
    if (op == 0) {
      if constexpr (NPASS == 3) {
        src = (pass == 1) ? Alo : Ahi;
        ld = (pass == 1) ? lda1 : lda0;
      } else {
        src = Ahi;
        ld = lda0;
      }
    } else {
      if constexpr (NPASS >= 2) {
        src = (pass == ((NPASS == 3) ? 2 : 1)) ? Blo : Bhi;
      } else {
        src = Bhi;
      }
      ld = ldb;
    }
    const long bstr = op ? sB : sA;
    const long rb = (op ? bn : bm) + (long)half * 128;
    const int r0 = tid >> 3;                 // 0..63 (row within 64-row slab)
    const int c0 = (tid & 7) ^ (r0 & 7);     // pre-swizzled source chunk
    const u16* g = src + bz * bstr + (rb + r0) * ld + kk0 + c0 * 8;
    u16* lp = &smem[buf][op][half][0][0] + (tid >> 6) * 512;  // wave-uniform dest
    gload16(g, lp);
    gload16(g + 64 * ld, lp + 4096);         // rows +64: (r0+64)&7 == r0&7
  };

  // hoisted lane pointers (r16): fragment read = ptr + compile-time m*2048
  const char* aptr[2][2];
  const char* bptr[2][2];
#pragma unroll
  for (int p = 0; p < 2; ++p)
#pragma unroll
    for (int kk = 0; kk < 2; ++kk) {
      const int swz = ((((kk << 2) + kl) ^ l7) << 4);
      aptr[p][kk] = (const char*)&smem[p][0][wr][0][0] + l15 * 128 + swz;
      bptr[p][kk] = (const char*)&smem[p][1][wc >> 1][0][0] + (wc & 1) * 8192 +
                    l15 * 128 + swz;
    }

  f32x4 acc[8][4] = {};

  if constexpr (SCHED == 0) {
    // r14 prologue: stage B(0),A(0),A(1); drain all but A(1)
    stage(0, 1, 0, 0); stage(0, 1, 1, 0); stage(0, 0, 0, 0); stage(0, 0, 1, 0);
    stage(1, 0, 0, 1); stage(1, 0, 1, 1);
    asm volatile("s_waitcnt vmcnt(4)" ::: "memory");
    __builtin_amdgcn_s_barrier();
  } else {
    // r15 prologue: confirm tile0 fully, then put tile1 in flight
    stage(0, 1, 0, 0); stage(0, 1, 1, 0); stage(0, 0, 0, 0); stage(0, 0, 1, 0);
    asm volatile("s_waitcnt vmcnt(0)" ::: "memory");
    __builtin_amdgcn_s_barrier();
    stage(1, 0, 0, 1); stage(1, 0, 1, 1);
    stage(1, 1, 0, 1); stage(1, 1, 1, 1);
  }

  bf16x8 af[8][2], bl[2][2], bh[2][2];

#pragma unroll 1
  for (int t2 = 0; t2 < NT; t2 += 2) {
#pragma unroll
    for (int u = 0; u < 2; ++u) {
      const int t = t2 + u;
      const int P = u;  // buffer parity (t2 even) — compile-time in unrolled body
      // ---- Phase A: read af[8]+bl; (SCHED=0: stage B(t+1)); MFMA n0-1;
      //      bh issued at end, dangling across the barrier (r13)
#pragma unroll
      for (int m = 0; m < 8; ++m) {
        af[m][0] = *(const bf16x8*)(aptr[P][0] + m * 2048);
        af[m][1] = *(const bf16x8*)(aptr[P][1] + m * 2048);
      }
#pragma unroll
      for (int n = 0; n < 2; ++n) {
        bl[n][0] = *(const bf16x8*)(bptr[P][0] + n * 2048);
        bl[n][1] = *(const bf16x8*)(bptr[P][1] + n * 2048);
      }
      if constexpr (SCHED == 0) {
        stage(t + 1, 1, 0, P ^ 1);
        stage(t + 1, 1, 1, P ^ 1);
      }
      __builtin_amdgcn_s_setprio(1);
#pragma unroll
      for (int m = 0; m < 4; ++m)
#pragma unroll
        for (int n = 0; n < 2; ++n) {
          acc[m][n] = MFMA16(af[m][0], bl[n][0], acc[m][n]);
          acc[m][n] = MFMA16(af[m][1], bl[n][1], acc[m][n]);
        }
#pragma unroll
      for (int m = 0; m < 4; ++m)
#pragma unroll
        for (int n = 0; n < 2; ++n) {
          acc[4 + m][n] = MFMA16(af[4 + m][0], bl[n][0], acc[4 + m][n]);
          acc[4 + m][n] = MFMA16(af[4 + m][1], bl[n][1], acc[4 + m][n]);
        }
      __builtin_amdgcn_s_setprio(0);
      __builtin_amdgcn_sched_barrier(0);   // pin: all af/bl reads issued first
#pragma unroll
      for (int n = 0; n < 2; ++n) {
        bh[n][0] = *(const bf16x8*)(bptr[P][0] + (2 + n) * 2048);
        bh[n][1] = *(const bf16x8*)(bptr[P][1] + (2 + n) * 2048);
      }
      __builtin_amdgcn_sched_barrier(0);   // pin: bh last in DS issue order
      asm volatile("s_waitcnt lgkmcnt(4)" ::: "memory");  // af+bl done; bh dangles
      __builtin_amdgcn_s_barrier();
      // ---- Phase B: stage A(t+2); MFMA n2-3; merged end-of-phase sync.
      stage(t + 2, 0, 0, P);
      stage(t + 2, 0, 1, P);
      __builtin_amdgcn_s_setprio(1);
#pragma unroll
      for (int m = 0; m < 4; ++m)
#pragma unroll
        for (int n = 0; n < 2; ++n) {
          acc[4 + m][2 + n] = MFMA16(af[4 + m][0], bh[n][0], acc[4 + m][2 + n]);
          acc[4 + m][2 + n] = MFMA16(af[4 + m][1], bh[n][1], acc[4 + m][2 + n]);
        }
#pragma unroll
      for (int m = 0; m < 4; ++m)
#pragma unroll
        for (int n = 0; n < 2; ++n) {
          acc[m][2 + n] = MFMA16(af[m][0], bh[n][0], acc[m][2 + n]);
          acc[m][2 + n] = MFMA16(af[m][1], bh[n][1], acc[m][2 + n]);
        }
      __builtin_amdgcn_s_setprio(0);
      asm volatile("s_waitcnt lgkmcnt(0)" ::: "memory");  // bh fully drained
      if constexpr (SCHED == 1) {
        stage(t + 2, 1, 0, P);   // B(t+2) into bh-region (dead for this wave)
        stage(t + 2, 1, 1, P);
      }
      if (t < NT - 2)
        asm volatile("s_waitcnt vmcnt(4)" ::: "memory");
      else
        asm volatile("s_waitcnt vmcnt(0)" ::: "memory");
      __builtin_amdgcn_s_barrier();
    }
  }

  // epilogue
  const int fr = l15;
  const int rg = (lane >> 4) * 4;
#pragma unroll
  for (int m = 0; m < 8; ++m) {
#pragma unroll
    for (int n = 0; n < 4; ++n) {
      long col = bn + wc * 64 + n * 16 + fr;
      float bv = 0.f;
      if constexpr (EPI == 1 || EPI == 2) {
        if (bias) bv = bias[col];
      }
#pragma unroll
      for (int j = 0; j < 4; ++j) {
        long row = bm + wr * 128 + m * 16 + rg + j;
        long idx = bz * sC + row * (long)ldc + col;
        float v = acc[m][n][j];
        if constexpr (EPI == 0) {
          Cf[idx] = v;
        } else if constexpr (EPI == 1) {
          v += bv;
          u16 h = f2bf(v);
          u16 l2 = f2bf(v - bf2f(h));
          Chi[idx] = h;
          Clo[idx] = l2;
        } else if constexpr (EPI == 2) {
          Cf[idx] = tanhf(v + bv);
        } else {
          Chi[idx] = f2bf(v);
        }
      }
    }
  }
}

// input [BT,1024] fp32 -> cat hi cols [1024..2048) (row stride 2048) + inLo [BT,1024]
__global__ void split_input_k(const float* __restrict__ in, u16* __restrict__ catHi,
                              u16* __restrict__ inLo) {
  long i = (long)blockIdx.x * 256 + threadIdx.x;
  const float4 v = ((const float4*)in)[i];
  long r = i >> 8;
  int c = (int)(i & 255);
  ushort4 hs, ls;
  hs.x = f2bf(v.x); ls.x = f2bf(v.x - bf2f(hs.x));
  hs.y = f2bf(v.y); ls.y = f2bf(v.y - bf2f(hs.y));
  hs.z = f2bf(v.z); ls.z = f2bf(v.z - bf2f(hs.z));
  hs.w = f2bf(v.w); ls.w = f2bf(v.w - bf2f(hs.w));
  *(ushort4*)&catHi[r * 2048 + 1024 + c * 4] = hs;
  *(ushort4*)&inLo[r * 1024 + c * 4] = ls;
}

__global__ void split_plain_k(const float* __restrict__ src, u16* __restrict__ hi,
                              u16* __restrict__ lo) {
  long i = (long)blockIdx.x * 256 + threadIdx.x;
  const float4 v = ((const float4*)src)[i];
  long base = i * 4;
  ushort4 hs, ls;
  hs.x = f2bf(v.x); ls.x = f2bf(v.x - bf2f(hs.x));
  hs.y = f2bf(v.y); ls.y = f2bf(v.y - bf2f(hs.y));
  hs.z = f2bf(v.z); ls.z = f2bf(v.z - bf2f(hs.z));
  hs.w = f2bf(v.w); ls.w = f2bf(v.w - bf2f(hs.w));
  *(ushort4*)&hi[base] = hs;
  *(ushort4*)&lo[base] = ls;
}

// vectorized ctx split+transpose (r12): float4 loads, ushort4 stores,
// LDS [64][68] transpose for coalesced ctxT writes.
__global__ __launch_bounds__(256) void ctx_split_trans_k(
    const float* __restrict__ ctx, u16* __restrict__ ctxHi,
    u16* __restrict__ ctxLo, u16* __restrict__ ctxTHi) {
  __shared__ u16 th[64][68];
  const int s0 = blockIdx.x * 64, h0 = blockIdx.y * 64, b = blockIdx.z;
  const int tid = threadIdx.x;
#pragma unroll
  for (int i = 0; i < 4; ++i) {
    int fl = i * 256 + tid;   // 0..1023
    int s = fl >> 4;          // 0..63
    int hq = fl & 15;         // float4 index within 64-col row
    long gi = ((long)b * Ss + s0 + s) * Hh + h0 + hq * 4;
    float4 v = *(const float4*)&ctx[gi];
    ushort4 hs, ls;
    hs.x = f2bf(v.x); ls.x = f2bf(v.x - bf2f(hs.x));
    hs.y = f2bf(v.y); ls.y = f2bf(v.y - bf2f(hs.y));
    hs.z = f2bf(v.z); ls.z = f2bf(v.z - bf2f(hs.z));
    hs.w = f2bf(v.w); ls.w = f2bf(v.w - bf2f(hs.w));
    *(ushort4*)&ctxHi[gi] = hs;
    *(ushort4*)&ctxLo[gi] = ls;
    *(ushort4*)&th[s][hq * 4] = hs;
  }
  __syncthreads();
#pragma unroll
  for (int i = 0; i < 4; ++i) {
    int fl = i * 256 + tid;
    int h = fl >> 4;          // 0..63
    int sq = fl & 15;         // ushort4 index along s
    ushort4 t;
    t.x = th[sq * 4 + 0][h];
    t.y = th[sq * 4 + 1][h];
    t.z = th[sq * 4 + 2][h];
    t.w = th[sq * 4 + 3][h];
    long go = ((long)b * Hh + h0 + h) * Ss + s0 + sq * 4;
    *(ushort4*)&ctxTHi[go] = t;
  }
}

__global__ __launch_bounds__(256) void softmax_k(const float* __restrict__ sc,
                                                 u16* __restrict__ alignHi) {
  long row = blockIdx.x;
  const float* x = sc + row * 2048;
  int tid = threadIdx.x;
  int lane = tid & 63, wave = tid >> 6;
  float4 v0 = ((const float4*)x)[tid];
  float4 v1 = ((const float4*)x)[tid + 256];
  float m = fmaxf(fmaxf(fmaxf(v0.x, v0.y), fmaxf(v0.z, v0.w)),
                  fmaxf(fmaxf(v1.x, v1.y), fmaxf(v1.z, v1.w)));
#pragma unroll
  for (int o = 1; o < 64; o <<= 1) m = fmaxf(m, __shfl_xor(m, o));
  __shared__ float red[8];
  if (lane == 0) red[wave] = m;
  __syncthreads();
  m = fmaxf(fmaxf(red[0], red[1]), fmaxf(red[2], red[3]));
  float e0 = expf(v0.x - m), e1 = expf(v0.y - m), e2 = expf(v0.z - m), e3 = expf(v0.w - m);
  float e4 = expf(v1.x - m), e5 = expf(v1.y - m), e6 = expf(v1.z - m), e7 = expf(v1.w - m);
  float s = ((e0 + e1) + (e2 + e3)) + ((e4 + e5) + (e6 + e7));
#pragma unroll
  for (int o = 1; o < 64; o <<= 1) s += __shfl_xor(s, o);
  if (lane == 0) red[4 + wave] = s;
  __syncthreads();
  s = (red[4] + red[5]) + (red[6] + red[7]);
  float inv = 1.0f / s;
  ushort4 h0, h1;
  h0.x = f2bf(e0 * inv); h0.y = f2bf(e1 * inv); h0.z = f2bf(e2 * inv); h0.w = f2bf(e3 * inv);
  h1.x = f2bf(e4 * inv); h1.y = f2bf(e5 * inv); h1.z = f2bf(e6 * inv); h1.w = f2bf(e7 * inv);
  *(ushort4*)&alignHi[row * 2048 + tid * 4] = h0;
  *(ushort4*)&alignHi[row * 2048 + 1024 + tid * 4] = h1;
}

extern "C" void kernel_launch(void* const* d_in, const int* in_sizes, int n_in,
                              void* d_out, int out_size, void* d_ws, size_t ws_size,
                              hipStream_t stream) {
  const float* input = (const float*)d_in[0];
  const float* context = (const float*)d_in[1];
  const float* affine_w = (const float*)d_in[2];
  const float* affine_b = (const float*)d_in[3];
  const float* mlp_w = (const float*)d_in[4];
  const float* mlp_b = (const float*)d_in[5];

  size_t off = 0;
  char* ws = (char*)d_ws;
  auto take = [&](size_t bytes) -> void* {
    void* p = ws + off;
    off += (bytes + 255) & ~(size_t)255;
    return p;
  };
  const size_t NBIG = 33554432;  // BT*2048
  u16* catHi   = (u16*)take(NBIG * 2);   // 64MB  [c | input] hi, [BT,2048]
  u16* inLo    = (u16*)take(NBIG);       // 32MB  input lo [BT,1024]
  u16* ctxHi   = (u16*)take(NBIG * 2);   // 64MB  [B,S,H]
  u16* ctxLo   = (u16*)take(NBIG * 2);   // 64MB
  u16* ctxTHi  = (u16*)take(NBIG * 2);   // 64MB  [B,H,S]
  u16* alignHi = (u16*)take(NBIG * 2);   // 64MB  [BT,S]
  u16* wHi  = (u16*)take(1048576 * 2);
  u16* wLo  = (u16*)take(1048576 * 2);
  u16* mwHi = (u16*)take(2097152 * 2);
  u16* mwLo = (u16*)take(2097152 * 2);
  size_t fixed_off = off;
  // scores chunk: nbc batches at 8MB each, adaptive to ws_size
  int nbc = 16;
  while (nbc > 2 && fixed_off + (size_t)nbc * Tt * Ss * 4 + 4096 > ws_size) nbc >>= 1;
  float* scores = (float*)take((size_t)nbc * Tt * Ss * 4);
  // h_t hi/lo planes live in d_out (overwritten by the final fp32 output)
  u16* htHi = (u16*)d_out;
  u16* htLo = htHi + 16777216;

  if (ws_size < off) {  // fail soft: absmax == max|ref| signals ws starvation
    hipMemsetAsync(d_out, 0, (size_t)out_size * 4, stream);
    return;
  }

  split_plain_k<<<1024, 256, 0, stream>>>(affine_w, wHi, wLo);
  split_plain_k<<<2048, 256, 0, stream>>>(mlp_w, mwHi, mwLo);
  split_input_k<<<16384, 256, 0, stream>>>(input, catHi, inLo);
  ctx_split_trans_k<<<dim3(32, 16, 16), 256, 0, stream>>>(context, ctxHi, ctxLo,
                                                          ctxTHi);
  // GEMM1: h_t = input*Wa^T + b  (M=16384,N=1024,K=1024, 3-pass; 1 blk/CU -> SCHED=0)
  gemm8<3, 1024, 1, 0><<<dim3(64, 4, 1), 512, 0, stream>>>(
      catHi + 1024, inLo, wHi, wLo, 2048, 1024, 1024, 0, 0, 0, affine_b,
      nullptr, htHi, htLo, 1024);
  // GEMM2 + softmax in chunks of nbc batches (512 blocks, 2 blk/CU -> SCHED=1)
  for (int ch = 0; ch < 16 / nbc; ++ch) {
    long bo = (long)ch * nbc;
    gemm8<3, 1024, 0, 1><<<dim3(4, 8, nbc), 512, 0, stream>>>(
        htHi + bo * Tt * Hh, htLo + bo * Tt * Hh, ctxHi + bo * Ss * Hh,
        ctxLo + bo * Ss * Hh, 1024, 1024, 1024, (long)Tt * Hh, (long)Ss * Hh,
        (long)Tt * Ss, nullptr, scores, nullptr, nullptr, 2048);
    softmax_k<<<nbc * 1024, 256, 0, stream>>>(scores, alignHi + bo * Tt * Ss);
  }
  // GEMM3: c[b] = align[b]*ctxT[b]^T (1-pass; 1 blk/CU -> SCHED=0)
  gemm8<1, 2048, 3, 0><<<dim3(4, 4, 16), 512, 0, stream>>>(
      alignHi, nullptr, ctxTHi, nullptr, 2048, 0, 2048, (long)Tt * Ss, (long)Hh * Ss,
      (long)Tt * 2048, nullptr, nullptr, catHi, nullptr, 2048);
  // GEMM4: out = tanh(cat*Wmlp^T + b)  (1-pass; 1 blk/CU -> SCHED=0)
  gemm8<1, 2048, 2, 0><<<dim3(64, 4, 1), 512, 0, stream>>>(
      catHi, nullptr, mwHi, nullptr, 2048, 0, 2048, 0, 0, 0, mlp_b, (float*)d_out,
      nullptr, nullptr, 1024);
  (void)in_sizes; (void)n_in; (void)ws_size;
}